// Round 1
// baseline (575.579 us; speedup 1.0000x reference)
//
#include <hip/hip_runtime.h>
#include <hip/hip_bf16.h>
#include <math.h>

using bf16 = __hip_bfloat16;

#define B_SZ    8
#define C_DIM   512
#define N_TOK   1024
#define NHEAD   8
#define HDIM    64
#define LN_EPSF 1e-5f

// Swizzled float4-quad slot inside a 64x64 fp32 tile (row pitch 64).
// quad ^= (row>>2): audited to give <=2-way bank conflicts for every access
// pattern used below (2-way is free on gfx950).
#define SWQ(row, qd) (((row) << 6) + ((((qd) ^ ((row) >> 2)) & 15) << 2))

__device__ __forceinline__ float b2f(unsigned short u) {
    union { unsigned int i; float f; } v; v.i = ((unsigned int)u) << 16; return v.f;
}
__device__ __forceinline__ float4 cvt4(ushort4 u) {
    return make_float4(b2f(u.x), b2f(u.y), b2f(u.z), b2f(u.w));
}

// ---------------- Kernel A: LayerNorm row stats (mu, rsigma) ----------------
// grid 128, block 256. Each block: 64 rows, 4 thread-groups of 128 channels.
__global__ __launch_bounds__(256) void ln_stats_kernel(
        const float* __restrict__ x, float* __restrict__ mu, float* __restrict__ rsig) {
    __shared__ float red_s[4][64];
    __shared__ float red_q[4][64];
    const int t  = threadIdx.x;
    const int rl = t & 63;
    const int cg = t >> 6;
    const int r0 = blockIdx.x * 64;
    const int b  = r0 >> 10;
    const int n  = (r0 & 1023) + rl;
    const float* xp = x + (size_t)b * C_DIM * N_TOK + n;
    float s = 0.f, q = 0.f;
    #pragma unroll 4
    for (int i = 0; i < 128; ++i) {
        float v = xp[(size_t)(cg * 128 + i) * N_TOK];
        s += v; q += v * v;
    }
    red_s[cg][rl] = s; red_q[cg][rl] = q;
    __syncthreads();
    if (cg == 0) {
        float S = red_s[0][rl] + red_s[1][rl] + red_s[2][rl] + red_s[3][rl];
        float Q = red_q[0][rl] + red_q[1][rl] + red_q[2][rl] + red_q[3][rl];
        float m   = S * (1.0f / C_DIM);
        float var = Q * (1.0f / C_DIM) - m * m;
        mu[r0 + rl]   = m;
        rsig[r0 + rl] = rsqrtf(var + LN_EPSF);
    }
}

// ------- Kernel B: fused LN-normalize + QKV GEMM + bias + RoPE + scatter -------
// grid (128 row-tiles, 24 col-tiles), block 256. Each col-tile of 64 is exactly
// one (which in {q,k,v}, head) pair since 1536/64 = 24 = 3*8.
__global__ __launch_bounds__(256) void qkv_rope_kernel(
        const float* __restrict__ x, const float* __restrict__ w,
        const float* __restrict__ bias, const float* __restrict__ gamma,
        const float* __restrict__ beta, const float* __restrict__ mu,
        const float* __restrict__ rsig,
        bf16* __restrict__ qb, bf16* __restrict__ kb, bf16* __restrict__ vb) {
    __shared__ float As[32 * 64];   // [kc][row]
    __shared__ float Bs[32 * 64];   // [kc][j]
    __shared__ float Os[64 * 64];   // epilogue tile

    const int t  = threadIdx.x;
    const int r0 = blockIdx.x * 64;
    const int jt = blockIdx.y;
    const int j0 = jt * 64;
    const int b  = r0 >> 10;
    const int n0 = r0 & 1023;
    const int tx = t & 15, ty = t >> 4;

    // A-load mapping: one row per thread, 4 k-slices per pass
    const int a_n  = t & 63;
    const int a_c0 = t >> 6;
    const float l_mu = mu[r0 + a_n];
    const float l_rs = rsig[r0 + a_n];
    const float* xrow = x + (size_t)b * C_DIM * N_TOK + n0 + a_n;
    // B-load mapping: 8 consecutive k per thread (2x float4 from global)
    const int b_j  = t >> 2;
    const int b_c0 = (t & 3) * 8;

    float acc[4][4] = {{0.f, 0.f, 0.f, 0.f}, {0.f, 0.f, 0.f, 0.f},
                       {0.f, 0.f, 0.f, 0.f}, {0.f, 0.f, 0.f, 0.f}};

    for (int k0 = 0; k0 < C_DIM; k0 += 32) {
        #pragma unroll
        for (int i = 0; i < 8; ++i) {
            const int cl = a_c0 + i * 4;
            const int c  = k0 + cl;
            float xv = xrow[(size_t)c * N_TOK];
            As[(cl << 6) + a_n] = (xv - l_mu) * l_rs * gamma[c] + beta[c];
        }
        {
            const float* wp = w + (size_t)(j0 + b_j) * C_DIM + k0 + b_c0;
            float4 w0 = *(const float4*)(wp);
            float4 w1 = *(const float4*)(wp + 4);
            Bs[((b_c0 + 0) << 6) + b_j] = w0.x;
            Bs[((b_c0 + 1) << 6) + b_j] = w0.y;
            Bs[((b_c0 + 2) << 6) + b_j] = w0.z;
            Bs[((b_c0 + 3) << 6) + b_j] = w0.w;
            Bs[((b_c0 + 4) << 6) + b_j] = w1.x;
            Bs[((b_c0 + 5) << 6) + b_j] = w1.y;
            Bs[((b_c0 + 6) << 6) + b_j] = w1.z;
            Bs[((b_c0 + 7) << 6) + b_j] = w1.w;
        }
        __syncthreads();
        #pragma unroll 8
        for (int kc = 0; kc < 32; ++kc) {
            const float4 a4 = *(const float4*)&As[(kc << 6) + ty * 4];
            const float4 b4 = *(const float4*)&Bs[(kc << 6) + tx * 4];
            const float av[4] = {a4.x, a4.y, a4.z, a4.w};
            const float bv[4] = {b4.x, b4.y, b4.z, b4.w};
            #pragma unroll
            for (int i = 0; i < 4; ++i) {
                #pragma unroll
                for (int j = 0; j < 4; ++j) {
                    acc[i][j] = fmaf(av[i], bv[j], acc[i][j]);
                }
            }
        }
        __syncthreads();
    }

    // bias + stage tile to LDS (RoPE needs cross-thread partner d^32)
    {
        const float4 bi = *(const float4*)&bias[j0 + tx * 4];
        #pragma unroll
        for (int i = 0; i < 4; ++i) {
            *(float4*)&Os[((ty * 4 + i) << 6) + tx * 4] =
                make_float4(acc[i][0] + bi.x, acc[i][1] + bi.y,
                            acc[i][2] + bi.z, acc[i][3] + bi.w);
        }
    }
    __syncthreads();

    const int which = jt >> 3;       // 0=q 1=k 2=v
    const int head  = jt & 7;
    bf16* dst = (which == 0) ? qb : ((which == 1) ? kb : vb);
    const int d = t & 63;
    bf16* op = dst + ((size_t)(b * NHEAD + head) * N_TOK + n0) * HDIM + d;
    if (which < 2) {
        // Reference convention: cos/sin index d>>1 (repeat), partner d^32.
        const float fr  = __expf((float)(d >> 1) * (-9.210340371976184f / 32.0f));
        const float sgn = (d < 32) ? -1.0f : 1.0f;
        #pragma unroll 4
        for (int nl = t >> 6; nl < 64; nl += 4) {
            float v0 = Os[(nl << 6) + d];
            float v1 = Os[(nl << 6) + (d ^ 32)];
            float sv, cv;
            sincosf((float)(n0 + nl) * fr, &sv, &cv);
            op[(size_t)nl * HDIM] = __float2bfloat16(v0 * cv + sgn * v1 * sv);
        }
    } else {
        #pragma unroll 4
        for (int nl = t >> 6; nl < 64; nl += 4) {
            op[(size_t)nl * HDIM] = __float2bfloat16(Os[(nl << 6) + d]);
        }
    }
}

// ---------------- Kernel C: flash-style attention ----------------
// grid (16 q-tiles, 64 head-batches), block 256, fp32 VALU, online softmax.
__global__ __launch_bounds__(256) void attn_kernel(
        const bf16* __restrict__ qg, const bf16* __restrict__ kg,
        const bf16* __restrict__ vg, float* __restrict__ out) {
    __shared__ float Qs[64 * 64];
    __shared__ float Ks[64 * 64];
    __shared__ float Vt[64 * 64];   // transposed: [d][kk]
    __shared__ float Ps[64 * 64];

    const int t  = threadIdx.x;
    const int tx = t & 15, ty = t >> 4;
    const int q0 = blockIdx.x * 64;
    const int bh = blockIdx.y;
    const int b  = bh >> 3, h = bh & 7;
    const size_t base = (size_t)bh * N_TOK * HDIM;

    {
        const int dq = t & 15;
        #pragma unroll 4
        for (int rl = t >> 4; rl < 64; rl += 16) {
            ushort4 u = *(const ushort4*)(qg + base + (size_t)(q0 + rl) * HDIM + dq * 4);
            *(float4*)&Qs[SWQ(rl, dq)] = cvt4(u);
        }
    }

    float m_i[4], l_i[4], o_acc[4][4];
    #pragma unroll
    for (int i = 0; i < 4; ++i) {
        m_i[i] = -3.0e38f; l_i[i] = 0.f;
        #pragma unroll
        for (int j = 0; j < 4; ++j) o_acc[i][j] = 0.f;
    }

    for (int kt = 0; kt < 16; ++kt) {
        const int k0 = kt * 64;
        {
            const int dq = t & 15;
            #pragma unroll 4
            for (int rl = t >> 4; rl < 64; rl += 16) {
                ushort4 uk = *(const ushort4*)(kg + base + (size_t)(k0 + rl) * HDIM + dq * 4);
                *(float4*)&Ks[SWQ(rl, dq)] = cvt4(uk);
                ushort4 uv = *(const ushort4*)(vg + base + (size_t)(k0 + rl) * HDIM + dq * 4);
                const int d0 = dq * 4, rq = rl >> 2, re = rl & 3;
                Vt[SWQ(d0 + 0, rq) + re] = b2f(uv.x);
                Vt[SWQ(d0 + 1, rq) + re] = b2f(uv.y);
                Vt[SWQ(d0 + 2, rq) + re] = b2f(uv.z);
                Vt[SWQ(d0 + 3, rq) + re] = b2f(uv.w);
            }
        }
        __syncthreads();

        // S = scale * Q K^T  (thread owns 4 qi x 4 kj)
        float s[4][4] = {{0.f, 0.f, 0.f, 0.f}, {0.f, 0.f, 0.f, 0.f},
                         {0.f, 0.f, 0.f, 0.f}, {0.f, 0.f, 0.f, 0.f}};
        #pragma unroll 4
        for (int dq = 0; dq < 16; ++dq) {
            float4 a[4], c[4];
            #pragma unroll
            for (int i = 0; i < 4; ++i) a[i] = *(const float4*)&Qs[SWQ(ty * 4 + i, dq)];
            #pragma unroll
            for (int j = 0; j < 4; ++j) c[j] = *(const float4*)&Ks[SWQ(tx * 4 + j, dq)];
            #pragma unroll
            for (int i = 0; i < 4; ++i) {
                #pragma unroll
                for (int j = 0; j < 4; ++j) {
                    s[i][j] = fmaf(a[i].x, c[j].x, s[i][j]);
                    s[i][j] = fmaf(a[i].y, c[j].y, s[i][j]);
                    s[i][j] = fmaf(a[i].z, c[j].z, s[i][j]);
                    s[i][j] = fmaf(a[i].w, c[j].w, s[i][j]);
                }
            }
        }

        // online softmax update; row reductions across the 16-lane tx group
        #pragma unroll
        for (int i = 0; i < 4; ++i) {
            #pragma unroll
            for (int j = 0; j < 4; ++j) s[i][j] *= 0.125f;
            float mt = fmaxf(fmaxf(s[i][0], s[i][1]), fmaxf(s[i][2], s[i][3]));
            #pragma unroll
            for (int off = 8; off > 0; off >>= 1)
                mt = fmaxf(mt, __shfl_xor(mt, off, 16));
            const float mnew  = fmaxf(m_i[i], mt);
            const float alpha = __expf(m_i[i] - mnew);
            m_i[i] = mnew;
            float rs = 0.f;
            #pragma unroll
            for (int j = 0; j < 4; ++j) { s[i][j] = __expf(s[i][j] - mnew); rs += s[i][j]; }
            #pragma unroll
            for (int off = 8; off > 0; off >>= 1) rs += __shfl_xor(rs, off, 16);
            l_i[i] = l_i[i] * alpha + rs;
            #pragma unroll
            for (int j = 0; j < 4; ++j) o_acc[i][j] *= alpha;
            *(float4*)&Ps[SWQ(ty * 4 + i, tx)] = make_float4(s[i][0], s[i][1], s[i][2], s[i][3]);
        }
        __syncthreads();

        // O += P @ V   (thread owns 4 qi x 4 d; inner over kj quads)
        #pragma unroll 4
        for (int kq = 0; kq < 16; ++kq) {
            float4 p[4], v[4];
            #pragma unroll
            for (int i = 0; i < 4; ++i) p[i] = *(const float4*)&Ps[SWQ(ty * 4 + i, kq)];
            #pragma unroll
            for (int j = 0; j < 4; ++j) v[j] = *(const float4*)&Vt[SWQ(tx * 4 + j, kq)];
            #pragma unroll
            for (int i = 0; i < 4; ++i) {
                #pragma unroll
                for (int j = 0; j < 4; ++j) {
                    o_acc[i][j] = fmaf(p[i].x, v[j].x, o_acc[i][j]);
                    o_acc[i][j] = fmaf(p[i].y, v[j].y, o_acc[i][j]);
                    o_acc[i][j] = fmaf(p[i].z, v[j].z, o_acc[i][j]);
                    o_acc[i][j] = fmaf(p[i].w, v[j].w, o_acc[i][j]);
                }
            }
        }
        __syncthreads();
    }

    // epilogue: normalize, stage to LDS (reuse Qs), coalesced store
    #pragma unroll
    for (int i = 0; i < 4; ++i) {
        const float inv = 1.0f / l_i[i];
        *(float4*)&Qs[SWQ(ty * 4 + i, tx)] = make_float4(
            o_acc[i][0] * inv, o_acc[i][1] * inv, o_acc[i][2] * inv, o_acc[i][3] * inv);
    }
    __syncthreads();
    {
        const int ql = t & 63;
        float* op = out + ((size_t)b * C_DIM + h * HDIM) * N_TOK + q0 + ql;
        #pragma unroll 4
        for (int dl = t >> 6; dl < 64; dl += 4) {
            op[(size_t)dl * N_TOK] = Qs[SWQ(ql, dl >> 2) + (dl & 3)];
        }
    }
}

extern "C" void kernel_launch(void* const* d_in, const int* in_sizes, int n_in,
                              void* d_out, int out_size, void* d_ws, size_t ws_size,
                              hipStream_t stream) {
    const float* x     = (const float*)d_in[0];
    const float* w     = (const float*)d_in[1];
    const float* bias  = (const float*)d_in[2];
    const float* gamma = (const float*)d_in[3];
    const float* beta  = (const float*)d_in[4];
    float* out = (float*)d_out;

    char* ws = (char*)d_ws;
    float* mu   = (float*)ws;                       // 8192 f32
    float* rsig = (float*)(ws + 32768);             // 8192 f32
    bf16*  qb   = (bf16*)(ws + 65536);              // 8 MB
    bf16*  kb   = (bf16*)(ws + 65536 + 8388608);    // 8 MB
    bf16*  vb   = (bf16*)(ws + 65536 + 16777216);   // 8 MB   (total ~24.1 MB)

    hipLaunchKernelGGL(ln_stats_kernel, dim3(128), dim3(256), 0, stream, x, mu, rsig);
    hipLaunchKernelGGL(qkv_rope_kernel, dim3(128, 24), dim3(256), 0, stream,
                       x, w, bias, gamma, beta, mu, rsig, qb, kb, vb);
    hipLaunchKernelGGL(attn_kernel, dim3(16, 64), dim3(256), 0, stream, qb, kb, vb, out);
}

// Round 2
// 344.462 us; speedup vs baseline: 1.6710x; 1.6710x over previous
//
#include <hip/hip_runtime.h>
#include <hip/hip_bf16.h>
#include <math.h>

using bf16 = __hip_bfloat16;
typedef __attribute__((ext_vector_type(8))) short short8;
typedef __attribute__((ext_vector_type(4))) short short4_;
typedef __attribute__((ext_vector_type(4))) float floatx4;

#define C_DIM   512
#define N_TOK   1024
#define NHEAD   8
#define HDIM    64
#define LN_EPSF 1e-5f

// RNE float -> bf16 bits
__device__ __forceinline__ unsigned short f2b(float f) {
    union { float f; unsigned int u; } v; v.f = f;
    unsigned int r = v.u + 0x7FFFu + ((v.u >> 16) & 1u);
    return (unsigned short)(r >> 16);
}

// ---------------- Kernel A: LayerNorm row stats (mu, rsigma) ----------------
__global__ __launch_bounds__(256) void ln_stats_kernel(
        const float* __restrict__ x, float* __restrict__ mu, float* __restrict__ rsig) {
    __shared__ float red_s[4][64];
    __shared__ float red_q[4][64];
    const int t  = threadIdx.x;
    const int rl = t & 63;
    const int cg = t >> 6;
    const int r0 = blockIdx.x * 64;
    const int b  = r0 >> 10;
    const int n  = (r0 & 1023) + rl;
    const float* xp = x + (size_t)b * C_DIM * N_TOK + n;
    float s = 0.f, q = 0.f;
    #pragma unroll 4
    for (int i = 0; i < 128; ++i) {
        float v = xp[(size_t)(cg * 128 + i) * N_TOK];
        s += v; q += v * v;
    }
    red_s[cg][rl] = s; red_q[cg][rl] = q;
    __syncthreads();
    if (cg == 0) {
        float S = red_s[0][rl] + red_s[1][rl] + red_s[2][rl] + red_s[3][rl];
        float Q = red_q[0][rl] + red_q[1][rl] + red_q[2][rl] + red_q[3][rl];
        float m   = S * (1.0f / C_DIM);
        float var = Q * (1.0f / C_DIM) - m * m;
        mu[r0 + rl]   = m;
        rsig[r0 + rl] = rsqrtf(var + LN_EPSF);
    }
}

// ------- Kernel B: fused LN + QKV GEMM + bias + RoPE + scatter -------
// q written SCALED by 0.125 (exact pow2) as bf16 [bh][n][d]
// k written as bf16 [bh][n][d]
// v written TRANSPOSED as bf16 [bh][d][n]  (serves V^T A-fragments directly)
__global__ __launch_bounds__(256) void qkv_rope_kernel(
        const float* __restrict__ x, const float* __restrict__ w,
        const float* __restrict__ bias, const float* __restrict__ gamma,
        const float* __restrict__ beta, const float* __restrict__ mu,
        const float* __restrict__ rsig,
        unsigned short* __restrict__ qb, unsigned short* __restrict__ kb,
        unsigned short* __restrict__ vt) {
    __shared__ float As[32 * 64];   // [kc][row]
    __shared__ float Bs[32 * 64];   // [kc][j]
    __shared__ float Os[64 * 64];   // epilogue tile [n][j]

    const int t  = threadIdx.x;
    const int r0 = blockIdx.x * 64;
    const int jt = blockIdx.y;
    const int j0 = jt * 64;
    const int b  = r0 >> 10;
    const int n0 = r0 & 1023;
    const int tx = t & 15, ty = t >> 4;

    const int a_n  = t & 63;
    const int a_c0 = t >> 6;
    const float l_mu = mu[r0 + a_n];
    const float l_rs = rsig[r0 + a_n];
    const float* xrow = x + (size_t)b * C_DIM * N_TOK + n0 + a_n;
    const int b_j  = t >> 2;
    const int b_c0 = (t & 3) * 8;

    float acc[4][4] = {{0.f,0.f,0.f,0.f},{0.f,0.f,0.f,0.f},
                       {0.f,0.f,0.f,0.f},{0.f,0.f,0.f,0.f}};

    for (int k0 = 0; k0 < C_DIM; k0 += 32) {
        #pragma unroll
        for (int i = 0; i < 8; ++i) {
            const int cl = a_c0 + i * 4;
            const int c  = k0 + cl;
            float xv = xrow[(size_t)c * N_TOK];
            As[(cl << 6) + a_n] = (xv - l_mu) * l_rs * gamma[c] + beta[c];
        }
        {
            const float* wp = w + (size_t)(j0 + b_j) * C_DIM + k0 + b_c0;
            float4 w0 = *(const float4*)(wp);
            float4 w1 = *(const float4*)(wp + 4);
            Bs[((b_c0 + 0) << 6) + b_j] = w0.x;
            Bs[((b_c0 + 1) << 6) + b_j] = w0.y;
            Bs[((b_c0 + 2) << 6) + b_j] = w0.z;
            Bs[((b_c0 + 3) << 6) + b_j] = w0.w;
            Bs[((b_c0 + 4) << 6) + b_j] = w1.x;
            Bs[((b_c0 + 5) << 6) + b_j] = w1.y;
            Bs[((b_c0 + 6) << 6) + b_j] = w1.z;
            Bs[((b_c0 + 7) << 6) + b_j] = w1.w;
        }
        __syncthreads();
        #pragma unroll 8
        for (int kc = 0; kc < 32; ++kc) {
            const float4 a4 = *(const float4*)&As[(kc << 6) + ty * 4];
            const float4 b4 = *(const float4*)&Bs[(kc << 6) + tx * 4];
            const float av[4] = {a4.x, a4.y, a4.z, a4.w};
            const float bv[4] = {b4.x, b4.y, b4.z, b4.w};
            #pragma unroll
            for (int i = 0; i < 4; ++i)
                #pragma unroll
                for (int j = 0; j < 4; ++j)
                    acc[i][j] = fmaf(av[i], bv[j], acc[i][j]);
        }
        __syncthreads();
    }

    {
        const float4 bi = *(const float4*)&bias[j0 + tx * 4];
        #pragma unroll
        for (int i = 0; i < 4; ++i) {
            *(float4*)&Os[((ty * 4 + i) << 6) + tx * 4] =
                make_float4(acc[i][0] + bi.x, acc[i][1] + bi.y,
                            acc[i][2] + bi.z, acc[i][3] + bi.w);
        }
    }
    __syncthreads();

    const int which = jt >> 3;       // 0=q 1=k 2=v
    const int head  = jt & 7;
    if (which < 2) {
        unsigned short* dst = (which == 0) ? qb : kb;
        const float oscale = (which == 0) ? 0.125f : 1.0f;
        const int d = t & 63;
        unsigned short* op = dst + ((size_t)(b * NHEAD + head) * N_TOK + n0) * HDIM + d;
        // Reference RoPE: cos/sin index d>>1 (repeat), partner d^32.
        const float fr  = __expf((float)(d >> 1) * (-9.210340371976184f / 32.0f));
        const float sgn = (d < 32) ? -1.0f : 1.0f;
        #pragma unroll 4
        for (int nl = t >> 6; nl < 64; nl += 4) {
            float v0 = Os[(nl << 6) + d];
            float v1 = Os[(nl << 6) + (d ^ 32)];
            float sv, cv;
            sincosf((float)(n0 + nl) * fr, &sv, &cv);
            op[(size_t)nl * HDIM] = f2b((v0 * cv + sgn * v1 * sv) * oscale);
        }
    } else {
        // V transposed: vt[bh][d][n]; thread owns (d, 16 consecutive n)
        const int d  = t & 63;
        const int j0n = (t >> 6) * 16;
        unsigned short tmp[16];
        #pragma unroll
        for (int j = 0; j < 16; ++j)
            tmp[j] = f2b(Os[((j0n + j) << 6) + d]);
        unsigned short* op = vt + ((size_t)(b * NHEAD + head) * HDIM + d) * N_TOK + n0 + j0n;
        *(short8*)(op)     = *(const short8*)&tmp[0];
        *(short8*)(op + 8) = *(const short8*)&tmp[8];
    }
}

// ---------------- Kernel C: MFMA flash attention (S^T formulation) ----------------
// Computes S^T = K.Q^T (16x16x32 bf16 MFMA), online softmax over rows(=keys),
// O^T = V^T.P^T. No __syncthreads anywhere: per-wave LDS strip for the P
// C-layout -> B-layout round trip. q pre-scaled by 0.125; v pre-transposed.
__global__ __launch_bounds__(256) void attn_mfma_kernel(
        const unsigned short* __restrict__ qg, const unsigned short* __restrict__ kg,
        const unsigned short* __restrict__ vtg, float* __restrict__ out) {
    // per-wave, per-qsubtile P strip: [col(q) 16][key 64 pad 72] bf16
    __shared__ __align__(16) short Plds[4][2][16][72];

    const int t    = threadIdx.x;
    const int wv   = t >> 6;
    const int lane = t & 63;
    const int c    = lane & 15;
    const int quad = lane >> 4;
    const int bh   = blockIdx.y;
    const int b    = bh >> 3, h = bh & 7;
    const int qw   = blockIdx.x * 128 + wv * 32;   // wave's 32 q-rows

    const unsigned short* qb  = qg  + (size_t)bh * N_TOK * HDIM;
    const unsigned short* kb  = kg  + (size_t)bh * N_TOK * HDIM;
    const unsigned short* vtb = vtg + (size_t)bh * HDIM * N_TOK;

    // Q B-fragments: B[k=d][n=q] -> lane reads Q[qw+qt*16+c][ks*32+quad*8 ..+7]
    short8 qf[2][2];
    #pragma unroll
    for (int qt = 0; qt < 2; ++qt)
        #pragma unroll
        for (int ks = 0; ks < 2; ++ks)
            qf[qt][ks] = *(const short8*)(qb + (size_t)(qw + qt * 16 + c) * HDIM + ks * 32 + quad * 8);

    floatx4 o_acc[2][4];
    float m_i[2], l_i[2];
    #pragma unroll
    for (int qt = 0; qt < 2; ++qt) {
        m_i[qt] = -3.0e38f; l_i[qt] = 0.f;
        #pragma unroll
        for (int dt = 0; dt < 4; ++dt) o_acc[qt][dt] = (floatx4){0.f, 0.f, 0.f, 0.f};
    }

    #pragma unroll 1
    for (int kt = 0; kt < 16; ++kt) {
        const int k0 = kt * 64;

        // K A-frags: A[m=key][k=d]; V^T A-frags: A[m=d][k=key]
        short8 kf[4][2], vf[4][2];
        #pragma unroll
        for (int mt = 0; mt < 4; ++mt) {
            #pragma unroll
            for (int ks = 0; ks < 2; ++ks) {
                kf[mt][ks] = *(const short8*)(kb + (size_t)(k0 + mt * 16 + c) * HDIM + ks * 32 + quad * 8);
                vf[mt][ks] = *(const short8*)(vtb + (size_t)(mt * 16 + c) * N_TOK + k0 + ks * 32 + quad * 8);
            }
        }

        // S^T tiles: rows=keys (mt), cols=q (qt); C-layout row=quad*4+r, col=c
        floatx4 st[2][4];
        #pragma unroll
        for (int qt = 0; qt < 2; ++qt) {
            #pragma unroll
            for (int mt = 0; mt < 4; ++mt) {
                floatx4 z = (floatx4){0.f, 0.f, 0.f, 0.f};
                z = __builtin_amdgcn_mfma_f32_16x16x32_bf16(kf[mt][0], qf[qt][0], z, 0, 0, 0);
                st[qt][mt] = __builtin_amdgcn_mfma_f32_16x16x32_bf16(kf[mt][1], qf[qt][1], z, 0, 0, 0);
            }
        }

        // online softmax (per q-col c, over keys) + P -> LDS (bf16, [c][key])
        #pragma unroll
        for (int qt = 0; qt < 2; ++qt) {
            float mx = -3.0e38f;
            #pragma unroll
            for (int mt = 0; mt < 4; ++mt)
                #pragma unroll
                for (int r = 0; r < 4; ++r) mx = fmaxf(mx, st[qt][mt][r]);
            mx = fmaxf(mx, __shfl_xor(mx, 16));
            mx = fmaxf(mx, __shfl_xor(mx, 32));
            const float mnew  = fmaxf(m_i[qt], mx);
            const float alpha = __expf(m_i[qt] - mnew);
            m_i[qt] = mnew;
            float rs = 0.f;
            #pragma unroll
            for (int mt = 0; mt < 4; ++mt) {
                float p0 = __expf(st[qt][mt][0] - mnew);
                float p1 = __expf(st[qt][mt][1] - mnew);
                float p2 = __expf(st[qt][mt][2] - mnew);
                float p3 = __expf(st[qt][mt][3] - mnew);
                rs += (p0 + p1) + (p2 + p3);
                short4_ pk;
                pk.x = (short)f2b(p0); pk.y = (short)f2b(p1);
                pk.z = (short)f2b(p2); pk.w = (short)f2b(p3);
                *(short4_*)&Plds[wv][qt][c][mt * 16 + quad * 4] = pk;
            }
            rs += __shfl_xor(rs, 16);
            rs += __shfl_xor(rs, 32);
            l_i[qt] = l_i[qt] * alpha + rs;
            #pragma unroll
            for (int dt = 0; dt < 4; ++dt)
                #pragma unroll
                for (int r = 0; r < 4; ++r) o_acc[qt][dt][r] *= alpha;
        }

        // PV: O^T += V^T . P^T ; P^T B-frags from per-wave LDS strip
        #pragma unroll
        for (int qt = 0; qt < 2; ++qt) {
            const short8 pf0 = *(const short8*)&Plds[wv][qt][c][quad * 8];
            const short8 pf1 = *(const short8*)&Plds[wv][qt][c][32 + quad * 8];
            #pragma unroll
            for (int dt = 0; dt < 4; ++dt) {
                o_acc[qt][dt] = __builtin_amdgcn_mfma_f32_16x16x32_bf16(vf[dt][0], pf0, o_acc[qt][dt], 0, 0, 0);
                o_acc[qt][dt] = __builtin_amdgcn_mfma_f32_16x16x32_bf16(vf[dt][1], pf1, o_acc[qt][dt], 0, 0, 0);
            }
        }
    }

    // epilogue: O^T C-layout row=d=dt*16+quad*4+r, col=q=c; out[b][h*64+d][n]
    #pragma unroll
    for (int qt = 0; qt < 2; ++qt) {
        const float inv = 1.0f / l_i[qt];
        const int qcol = qw + qt * 16 + c;
        #pragma unroll
        for (int dt = 0; dt < 4; ++dt) {
            #pragma unroll
            for (int r = 0; r < 4; ++r) {
                const int d = dt * 16 + quad * 4 + r;
                out[((size_t)b * C_DIM + h * HDIM + d) * N_TOK + qcol] = o_acc[qt][dt][r] * inv;
            }
        }
    }
}

extern "C" void kernel_launch(void* const* d_in, const int* in_sizes, int n_in,
                              void* d_out, int out_size, void* d_ws, size_t ws_size,
                              hipStream_t stream) {
    const float* x     = (const float*)d_in[0];
    const float* w     = (const float*)d_in[1];
    const float* bias  = (const float*)d_in[2];
    const float* gamma = (const float*)d_in[3];
    const float* beta  = (const float*)d_in[4];
    float* out = (float*)d_out;

    char* ws = (char*)d_ws;
    float* mu   = (float*)ws;                                  // 32 KB
    float* rsig = (float*)(ws + 32768);                        // 32 KB
    unsigned short* qb = (unsigned short*)(ws + 65536);        // 8 MB
    unsigned short* kb = (unsigned short*)(ws + 65536 + 8388608);
    unsigned short* vt = (unsigned short*)(ws + 65536 + 16777216);

    hipLaunchKernelGGL(ln_stats_kernel, dim3(128), dim3(256), 0, stream, x, mu, rsig);
    hipLaunchKernelGGL(qkv_rope_kernel, dim3(128, 24), dim3(256), 0, stream,
                       x, w, bias, gamma, beta, mu, rsig, qb, kb, vt);
    hipLaunchKernelGGL(attn_mfma_kernel, dim3(8, 64), dim3(256), 0, stream, qb, kb, vt, out);
}

// Round 3
// 204.113 us; speedup vs baseline: 2.8199x; 1.6876x over previous
//
#include <hip/hip_runtime.h>
#include <hip/hip_bf16.h>
#include <math.h>

using bf16 = __hip_bfloat16;
typedef __attribute__((ext_vector_type(8))) short short8;
typedef __attribute__((ext_vector_type(4))) short short4_;
typedef __attribute__((ext_vector_type(4))) float floatx4;

#define C_DIM   512
#define N_TOK   1024
#define NHEAD   8
#define HDIM    64
#define LN_EPSF 1e-5f

// RNE float -> bf16 bits
__device__ __forceinline__ unsigned short f2b(float f) {
    union { float f; unsigned int u; } v; v.f = f;
    unsigned int r = v.u + 0x7FFFu + ((v.u >> 16) & 1u);
    return (unsigned short)(r >> 16);
}
__device__ __forceinline__ float b2f(unsigned short u) {
    union { unsigned int i; float f; } v; v.i = ((unsigned int)u) << 16; return v.f;
}

// ---------------- Kernel 1: prep = LN stats | sincos table | w->bf16 ----------------
// blocks [0,128): LN row stats; [128,256): rope table sc[n][32] float2(sin,cos);
// blocks [256,640): w fp32 -> bf16 (row-major [j][c] preserved, c contiguous).
__global__ __launch_bounds__(256) void prep_kernel(
        const float* __restrict__ x, const float* __restrict__ w,
        float* __restrict__ mu, float* __restrict__ rsig,
        float* __restrict__ sc, unsigned short* __restrict__ wbf) {
    __shared__ float red_s[4][64];
    __shared__ float red_q[4][64];
    const int bx = blockIdx.x;
    const int t  = threadIdx.x;
    if (bx < 128) {
        const int rl = t & 63;
        const int cg = t >> 6;
        const int r0 = bx * 64;
        const int b  = r0 >> 10;
        const int n  = (r0 & 1023) + rl;
        const float* xp = x + (size_t)b * C_DIM * N_TOK + n;
        float s = 0.f, q = 0.f;
        #pragma unroll 4
        for (int i = 0; i < 128; ++i) {
            float v = xp[(size_t)(cg * 128 + i) * N_TOK];
            s += v; q += v * v;
        }
        red_s[cg][rl] = s; red_q[cg][rl] = q;
        __syncthreads();
        if (cg == 0) {
            float S = red_s[0][rl] + red_s[1][rl] + red_s[2][rl] + red_s[3][rl];
            float Q = red_q[0][rl] + red_q[1][rl] + red_q[2][rl] + red_q[3][rl];
            float m   = S * (1.0f / C_DIM);
            float var = Q * (1.0f / C_DIM) - m * m;
            mu[r0 + rl]   = m;
            rsig[r0 + rl] = rsqrtf(var + LN_EPSF);
        }
    } else if (bx < 256) {
        const int idx = (bx - 128) * 256 + t;      // n*32 + f
        const int n = idx >> 5, f = idx & 31;
        const float fr = __expf((float)f * (-9.210340371976184f / 32.0f));
        float sv, cv;
        sincosf((float)n * fr, &sv, &cv);
        ((float2*)sc)[idx] = make_float2(sv, cv);
    } else {
        const size_t base = (size_t)((bx - 256) * 256 + t) * 8;
        const float4 w0 = *(const float4*)(w + base);
        const float4 w1 = *(const float4*)(w + base + 4);
        short8 pk;
        pk[0] = (short)f2b(w0.x); pk[1] = (short)f2b(w0.y);
        pk[2] = (short)f2b(w0.z); pk[3] = (short)f2b(w0.w);
        pk[4] = (short)f2b(w1.x); pk[5] = (short)f2b(w1.y);
        pk[6] = (short)f2b(w1.z); pk[7] = (short)f2b(w1.w);
        *(short8*)(wbf + base) = pk;
    }
}

// ---------------- Kernel 2: normalize + transpose: xnT[b*1024+n][c] bf16 ----------------
// grid (8 c-tiles, 16 n-tiles, 8 b), block 256. Tile 64c x 64n through LDS.
__global__ __launch_bounds__(256) void xnt_kernel(
        const float* __restrict__ x, const float* __restrict__ gamma,
        const float* __restrict__ beta, const float* __restrict__ mu,
        const float* __restrict__ rsig, unsigned short* __restrict__ xnT) {
    __shared__ short Sx[64][72];
    const int t  = threadIdx.x;
    const int c0 = blockIdx.x * 64;
    const int n0 = blockIdx.y * 64;
    const int b  = blockIdx.z;

    const int nq  = t & 15;          // n-quad (float4)
    const int crl = t >> 4;          // 16 c-rows per pass
    const int tok = b * N_TOK + n0 + nq * 4;
    const float4 m4 = *(const float4*)(mu + tok);
    const float4 r4 = *(const float4*)(rsig + tok);
    #pragma unroll
    for (int p = 0; p < 4; ++p) {
        const int c = c0 + p * 16 + crl;
        const float g = gamma[c], bt = beta[c];
        const float4 xv = *(const float4*)(x + (size_t)b * C_DIM * N_TOK + (size_t)c * N_TOK + n0 + nq * 4);
        Sx[nq * 4 + 0][p * 16 + crl] = (short)f2b((xv.x - m4.x) * r4.x * g + bt);
        Sx[nq * 4 + 1][p * 16 + crl] = (short)f2b((xv.y - m4.y) * r4.y * g + bt);
        Sx[nq * 4 + 2][p * 16 + crl] = (short)f2b((xv.z - m4.z) * r4.z * g + bt);
        Sx[nq * 4 + 3][p * 16 + crl] = (short)f2b((xv.w - m4.w) * r4.w * g + bt);
    }
    __syncthreads();
    const int oct = t & 7;
    #pragma unroll
    for (int p = 0; p < 2; ++p) {
        const int nr = p * 32 + (t >> 3);
        short8 v = *(const short8*)&Sx[nr][oct * 8];
        *(short8*)(xnT + (size_t)(b * N_TOK + n0 + nr) * C_DIM + c0 + oct * 8) = v;
    }
}

// ---------------- Kernel 3: QKV MFMA GEMM + bias + RoPE + scatter ----------------
// D[t][j] = xnT . wbf^T. Block 256 = 4 waves; block tile 128t x 128j; wave 64t x 64j
// (wave j-span = one full head). No __syncthreads. q scaled 0.125; v transposed.
__global__ __launch_bounds__(256) void qkv_mfma_kernel(
        const unsigned short* __restrict__ xnT, const unsigned short* __restrict__ wbf,
        const float* __restrict__ bias, const float* __restrict__ sc,
        unsigned short* __restrict__ qb, unsigned short* __restrict__ kb,
        unsigned short* __restrict__ vt) {
    __shared__ short Es[4][64][72];   // per-wave epilogue strip [t][d] (q/k only)

    const int t    = threadIdx.x;
    const int wv   = t >> 6;
    const int lane = t & 63;
    const int cl   = lane & 15;
    const int quad = lane >> 4;
    const int t0   = blockIdx.x * 128 + (wv & 1) * 64;
    const int j0w  = blockIdx.y * 128 + (wv >> 1) * 64;
    const int which = j0w >> 9;                 // 0=q 1=k 2=v
    const int h     = (j0w >> 6) & 7;
    const int b     = t0 >> 10;
    const int n0q   = t0 & 1023;
    const int bh    = b * NHEAD + h;

    const unsigned short* aptr = xnT + (size_t)(t0 + cl) * C_DIM + quad * 8;
    const unsigned short* bptr = wbf + (size_t)(j0w + cl) * C_DIM + quad * 8;

    floatx4 acc[4][4];
    #pragma unroll
    for (int i = 0; i < 4; ++i)
        #pragma unroll
        for (int j = 0; j < 4; ++j) acc[i][j] = (floatx4){0.f, 0.f, 0.f, 0.f};

    #pragma unroll 2
    for (int kt = 0; kt < 16; ++kt) {
        const int ko = kt * 32;
        short8 af[4], bfr[4];
        #pragma unroll
        for (int tt = 0; tt < 4; ++tt) af[tt]  = *(const short8*)(aptr + (size_t)tt * 16 * C_DIM + ko);
        #pragma unroll
        for (int jt = 0; jt < 4; ++jt) bfr[jt] = *(const short8*)(bptr + (size_t)jt * 16 * C_DIM + ko);
        #pragma unroll
        for (int tt = 0; tt < 4; ++tt)
            #pragma unroll
            for (int jt = 0; jt < 4; ++jt)
                acc[tt][jt] = __builtin_amdgcn_mfma_f32_16x16x32_bf16(af[tt], bfr[jt], acc[tt][jt], 0, 0, 0);
    }

    if (which == 2) {
        // V: direct transposed store vt[bh][d][n], 4 consecutive t packed (8 B)
        unsigned short* vtb = vt + (size_t)bh * HDIM * N_TOK;
        #pragma unroll
        for (int jt = 0; jt < 4; ++jt) {
            const int d = jt * 16 + cl;
            const float bj = bias[j0w + d];
            #pragma unroll
            for (int tt = 0; tt < 4; ++tt) {
                short4_ pk;
                #pragma unroll
                for (int r = 0; r < 4; ++r) pk[r] = (short)f2b(acc[tt][jt][r] + bj);
                *(short4_*)(vtb + (size_t)d * N_TOK + n0q + tt * 16 + quad * 4) = pk;
            }
        }
    } else {
        // Q/K: C-layout -> per-wave LDS strip -> row-wise RoPE + coalesced store
        #pragma unroll
        for (int tt = 0; tt < 4; ++tt)
            #pragma unroll
            for (int jt = 0; jt < 4; ++jt)
                #pragma unroll
                for (int r = 0; r < 4; ++r)
                    Es[wv][tt * 16 + quad * 4 + r][jt * 16 + cl] = (short)f2b(acc[tt][jt][r]);

        unsigned short* dst = ((which == 0) ? qb : kb) + (size_t)bh * N_TOK * HDIM;
        const float oscale = (which == 0) ? 0.125f : 1.0f;
        const int oct  = lane & 7;
        const int octp = oct ^ 4;                      // partner d^32
        const float sgn = (oct < 4) ? -1.0f : 1.0f;
        const float4 b0 = *(const float4*)(bias + j0w + oct * 8);
        const float4 b1 = *(const float4*)(bias + j0w + oct * 8 + 4);
        const float4 p0 = *(const float4*)(bias + j0w + octp * 8);
        const float4 p1 = *(const float4*)(bias + j0w + octp * 8 + 4);
        const float bs[8] = {b0.x, b0.y, b0.z, b0.w, b1.x, b1.y, b1.z, b1.w};
        const float bp[8] = {p0.x, p0.y, p0.z, p0.w, p1.x, p1.y, p1.z, p1.w};

        #pragma unroll
        for (int rr = 0; rr < 8; ++rr) {
            const int tl = rr * 8 + (lane >> 3);
            const short8 v8 = *(const short8*)&Es[wv][tl][oct * 8];
            const short8 q8 = *(const short8*)&Es[wv][tl][octp * 8];
            const float* scp = sc + ((size_t)(n0q + tl) * 32 + oct * 4) * 2;
            const float4 s0 = *(const float4*)scp;
            const float4 s1 = *(const float4*)(scp + 4);
            const float sv[4] = {s0.x, s0.z, s1.x, s1.z};
            const float cv[4] = {s0.y, s0.w, s1.y, s1.w};
            short8 pk;
            #pragma unroll
            for (int j = 0; j < 8; ++j) {
                const int f = j >> 1;
                const float val = b2f((unsigned short)v8[j]) + bs[j];
                const float par = b2f((unsigned short)q8[j]) + bp[j];
                pk[j] = (short)f2b((val * cv[f] + sgn * par * sv[f]) * oscale);
            }
            *(short8*)(dst + (size_t)(n0q + tl) * HDIM + oct * 8) = pk;
        }
    }
}

// ---------------- Kernel 4: MFMA flash attention (unchanged, verified) ----------------
__global__ __launch_bounds__(256) void attn_mfma_kernel(
        const unsigned short* __restrict__ qg, const unsigned short* __restrict__ kg,
        const unsigned short* __restrict__ vtg, float* __restrict__ out) {
    __shared__ __align__(16) short Plds[4][2][16][72];

    const int t    = threadIdx.x;
    const int wv   = t >> 6;
    const int lane = t & 63;
    const int c    = lane & 15;
    const int quad = lane >> 4;
    const int bh   = blockIdx.y;
    const int b    = bh >> 3, h = bh & 7;
    const int qw   = blockIdx.x * 128 + wv * 32;

    const unsigned short* qb  = qg  + (size_t)bh * N_TOK * HDIM;
    const unsigned short* kb  = kg  + (size_t)bh * N_TOK * HDIM;
    const unsigned short* vtb = vtg + (size_t)bh * HDIM * N_TOK;

    short8 qf[2][2];
    #pragma unroll
    for (int qt = 0; qt < 2; ++qt)
        #pragma unroll
        for (int ks = 0; ks < 2; ++ks)
            qf[qt][ks] = *(const short8*)(qb + (size_t)(qw + qt * 16 + c) * HDIM + ks * 32 + quad * 8);

    floatx4 o_acc[2][4];
    float m_i[2], l_i[2];
    #pragma unroll
    for (int qt = 0; qt < 2; ++qt) {
        m_i[qt] = -3.0e38f; l_i[qt] = 0.f;
        #pragma unroll
        for (int dt = 0; dt < 4; ++dt) o_acc[qt][dt] = (floatx4){0.f, 0.f, 0.f, 0.f};
    }

    #pragma unroll 1
    for (int kt = 0; kt < 16; ++kt) {
        const int k0 = kt * 64;
        short8 kf[4][2], vf[4][2];
        #pragma unroll
        for (int mt = 0; mt < 4; ++mt) {
            #pragma unroll
            for (int ks = 0; ks < 2; ++ks) {
                kf[mt][ks] = *(const short8*)(kb + (size_t)(k0 + mt * 16 + c) * HDIM + ks * 32 + quad * 8);
                vf[mt][ks] = *(const short8*)(vtb + (size_t)(mt * 16 + c) * N_TOK + k0 + ks * 32 + quad * 8);
            }
        }

        floatx4 st[2][4];
        #pragma unroll
        for (int qt = 0; qt < 2; ++qt) {
            #pragma unroll
            for (int mt = 0; mt < 4; ++mt) {
                floatx4 z = (floatx4){0.f, 0.f, 0.f, 0.f};
                z = __builtin_amdgcn_mfma_f32_16x16x32_bf16(kf[mt][0], qf[qt][0], z, 0, 0, 0);
                st[qt][mt] = __builtin_amdgcn_mfma_f32_16x16x32_bf16(kf[mt][1], qf[qt][1], z, 0, 0, 0);
            }
        }

        #pragma unroll
        for (int qt = 0; qt < 2; ++qt) {
            float mx = -3.0e38f;
            #pragma unroll
            for (int mt = 0; mt < 4; ++mt)
                #pragma unroll
                for (int r = 0; r < 4; ++r) mx = fmaxf(mx, st[qt][mt][r]);
            mx = fmaxf(mx, __shfl_xor(mx, 16));
            mx = fmaxf(mx, __shfl_xor(mx, 32));
            const float mnew  = fmaxf(m_i[qt], mx);
            const float alpha = __expf(m_i[qt] - mnew);
            m_i[qt] = mnew;
            float rs = 0.f;
            #pragma unroll
            for (int mt = 0; mt < 4; ++mt) {
                float e0 = __expf(st[qt][mt][0] - mnew);
                float e1 = __expf(st[qt][mt][1] - mnew);
                float e2 = __expf(st[qt][mt][2] - mnew);
                float e3 = __expf(st[qt][mt][3] - mnew);
                rs += (e0 + e1) + (e2 + e3);
                short4_ pk;
                pk.x = (short)f2b(e0); pk.y = (short)f2b(e1);
                pk.z = (short)f2b(e2); pk.w = (short)f2b(e3);
                *(short4_*)&Plds[wv][qt][c][mt * 16 + quad * 4] = pk;
            }
            rs += __shfl_xor(rs, 16);
            rs += __shfl_xor(rs, 32);
            l_i[qt] = l_i[qt] * alpha + rs;
            #pragma unroll
            for (int dt = 0; dt < 4; ++dt)
                #pragma unroll
                for (int r = 0; r < 4; ++r) o_acc[qt][dt][r] *= alpha;
        }

        #pragma unroll
        for (int qt = 0; qt < 2; ++qt) {
            const short8 pf0 = *(const short8*)&Plds[wv][qt][c][quad * 8];
            const short8 pf1 = *(const short8*)&Plds[wv][qt][c][32 + quad * 8];
            #pragma unroll
            for (int dt = 0; dt < 4; ++dt) {
                o_acc[qt][dt] = __builtin_amdgcn_mfma_f32_16x16x32_bf16(vf[dt][0], pf0, o_acc[qt][dt], 0, 0, 0);
                o_acc[qt][dt] = __builtin_amdgcn_mfma_f32_16x16x32_bf16(vf[dt][1], pf1, o_acc[qt][dt], 0, 0, 0);
            }
        }
    }

    #pragma unroll
    for (int qt = 0; qt < 2; ++qt) {
        const float inv = 1.0f / l_i[qt];
        const int qcol = qw + qt * 16 + c;
        #pragma unroll
        for (int dt = 0; dt < 4; ++dt) {
            #pragma unroll
            for (int r = 0; r < 4; ++r) {
                const int d = dt * 16 + quad * 4 + r;
                out[((size_t)b * C_DIM + h * HDIM + d) * N_TOK + qcol] = o_acc[qt][dt][r] * inv;
            }
        }
    }
}

extern "C" void kernel_launch(void* const* d_in, const int* in_sizes, int n_in,
                              void* d_out, int out_size, void* d_ws, size_t ws_size,
                              hipStream_t stream) {
    const float* x     = (const float*)d_in[0];
    const float* w     = (const float*)d_in[1];
    const float* bias  = (const float*)d_in[2];
    const float* gamma = (const float*)d_in[3];
    const float* beta  = (const float*)d_in[4];
    float* out = (float*)d_out;

    char* ws = (char*)d_ws;
    float* mu   = (float*)ws;                                   // 32 KB
    float* rsig = (float*)(ws + 32768);                         // 32 KB
    unsigned short* qb  = (unsigned short*)(ws + 65536);        // 8 MB
    unsigned short* kb  = (unsigned short*)(ws + 65536 + 8388608);
    unsigned short* vt  = (unsigned short*)(ws + 65536 + 16777216);
    unsigned short* xnT = (unsigned short*)(ws + 65536 + 25165824);  // 8 MB
    unsigned short* wbf = (unsigned short*)(ws + 65536 + 33554432);  // 1.5 MB
    float* sc           = (float*)(ws + 65536 + 35127296);           // 256 KB

    hipLaunchKernelGGL(prep_kernel, dim3(640), dim3(256), 0, stream, x, w, mu, rsig, sc, wbf);
    hipLaunchKernelGGL(xnt_kernel, dim3(8, 16, 8), dim3(256), 0, stream,
                       x, gamma, beta, mu, rsig, xnT);
    hipLaunchKernelGGL(qkv_mfma_kernel, dim3(64, 12), dim3(256), 0, stream,
                       xnT, wbf, bias, sc, qb, kb, vt);
    hipLaunchKernelGGL(attn_mfma_kernel, dim3(8, 64), dim3(256), 0, stream, qb, kb, vt, out);
}